// Round 11
// baseline (347.848 us; speedup 1.0000x reference)
//
#include <hip/hip_runtime.h>
#include <hip/hip_fp16.h>

#define N_NODES 50000
#define HID 128
#define CLS 64

#define NBINS 196         // ceil(50000/256) node bins
#define NBLK 256          // prep blocks (hist/scatter)
#define LBUF_CAP 4096     // per-bin CSR staging
#define WTOT 57344        // 3*128*128 + 64*128 weight elements
#define WSPLIT_BLOCKS 224 // WTOT / 256
#define GEMM0_TILES 782   // ceil(50000 / 64)
#define MEGA_BLOCKS 1024  // 256 prep + 768 gemm0
#define GEMM0_MEGA (MEGA_BLOCKS - NBLK)
#define AROW 136          // LDS row stride (128 + 8 pad)

typedef __attribute__((ext_vector_type(8))) _Float16 f16x8;
typedef __attribute__((ext_vector_type(4))) float f32x4;

// ---------------- K0: weight split (hi/lo fp16), tiny ----------------
__global__ __launch_bounds__(256) void wsplit_kernel(
    const float* __restrict__ W0, const float* __restrict__ W1,
    const float* __restrict__ W2, const float* __restrict__ Wl,
    __half* __restrict__ o0h, __half* __restrict__ o0l,
    __half* __restrict__ o1h, __half* __restrict__ o1l,
    __half* __restrict__ o2h, __half* __restrict__ o2l,
    __half* __restrict__ o3h, __half* __restrict__ o3l) {
    int widx = blockIdx.x * 256 + threadIdx.x;   // < WTOT by construction
    const float* W;
    __half *oh, *ol;
    int NCdim, local;
    if (widx < 16384)      { W = W0; oh = o0h; ol = o0l; NCdim = 128; local = widx; }
    else if (widx < 32768) { W = W1; oh = o1h; ol = o1l; NCdim = 128; local = widx - 16384; }
    else if (widx < 49152) { W = W2; oh = o2h; ol = o2l; NCdim = 128; local = widx - 32768; }
    else                   { W = Wl; oh = o3h; ol = o3l; NCdim = 64;  local = widx - 49152; }
    int nn = local >> 7;
    int k = local & 127;
    float v = W[(size_t)k * NCdim + nn];
    __half h = __float2half_rn(v);
    oh[local] = h;
    ol[local] = __float2half_rn(v - __half2float(h));
}

// ---------------- software barrier among the NBLK prep blocks only ------------
// Release: __threadfence (device scope) + device-scope atomicAdd.
// Acquire: __ATOMIC_ACQUIRE spin load (invalidates L1, orders later reads).
// gemm0 blocks never touch this -> prep never waits on gemm0.
__device__ __forceinline__ void prep_barrier(int* bar, int target) {
    __syncthreads();
    if (threadIdx.x == 0) {
        __threadfence();
        atomicAdd(bar, 1);
        while (__hip_atomic_load(bar, __ATOMIC_ACQUIRE,
                                 __HIP_MEMORY_SCOPE_AGENT) < target) {}
    }
    __syncthreads();
}

// ---------------- GEMM-0 body, LDS-staged (coalesced x reads) ----------
__device__ __forceinline__ void gemm0_lds_body(
    const float* __restrict__ x, const __half* __restrict__ Bh,
    const __half* __restrict__ Bl, __half* __restrict__ C, int M,
    int rowBase, __half* Als /* [64][AROW] */) {
    int t = threadIdx.x;
#pragma unroll
    for (int it = 0; it < 8; ++it) {
        int idx = it * 256 + t;          // 0..2047 = 64 rows x 32 float4
        int r = idx >> 5;
        int cq = idx & 31;
        int grow = rowBase + r;
        if (grow < M) {
            float4 v = *(const float4*)(x + (size_t)grow * 128 + cq * 4);
            __half2 h0 = __float22half2_rn(make_float2(v.x, v.y));
            __half2 h1 = __float22half2_rn(make_float2(v.z, v.w));
            __half2* dst = (__half2*)(Als + r * AROW + cq * 4);
            dst[0] = h0;
            dst[1] = h1;
        }
    }
    __syncthreads();
    int wave = t >> 6;
    int lane = t & 63;
    int m0 = rowBase + (wave << 4);
    if (m0 >= M) return;
    int mr = lane & 15;
    int kq = (lane >> 4) << 3;
    const __half* bh = Bh + (size_t)mr * 128 + kq;
    const __half* bl = Bl + (size_t)mr * 128 + kq;
    const __half* arow = Als + (wave * 16 + mr) * AROW + kq;

    f32x4 acc[8];
#pragma unroll
    for (int tt = 0; tt < 8; ++tt) acc[tt] = (f32x4){0.f, 0.f, 0.f, 0.f};
#pragma unroll
    for (int kc = 0; kc < 128; kc += 32) {
        f16x8 a = *(const f16x8*)(arow + kc);
#pragma unroll
        for (int tt = 0; tt < 8; ++tt) {
            f16x8 wh = *(const f16x8*)(bh + (size_t)tt * 16 * 128 + kc);
            f16x8 wl = *(const f16x8*)(bl + (size_t)tt * 16 * 128 + kc);
            acc[tt] = __builtin_amdgcn_mfma_f32_16x16x32_f16(a, wh, acc[tt], 0, 0, 0);
            acc[tt] = __builtin_amdgcn_mfma_f32_16x16x32_f16(a, wl, acc[tt], 0, 0, 0);
        }
    }
    int r0 = m0 + ((lane >> 4) << 2);
    int cc = lane & 15;
#pragma unroll
    for (int tt = 0; tt < 8; ++tt)
#pragma unroll
        for (int r = 0; r < 4; ++r) {
            if (r0 + r >= M) break;
            C[(size_t)(r0 + r) * 128 + tt * 16 + cc] =
                __float2half_rn(acc[tt][r]);
        }
}

// ---------------- K1 (mega): [prep chain w/ sw-barriers] || gemm0 ----------------
// Blocks b>=NBLK: gemm0 tiles, retire (no barrier participation).
// Blocks b<NBLK: hist -> bar -> binscan -> bar -> scatter -> bar -> csrplace.
__global__ __launch_bounds__(256) void prep_gemm0_mega_kernel(
    const int* __restrict__ row, const int* __restrict__ col,
    int* __restrict__ hist, int* __restrict__ cursorBase,
    int* __restrict__ binTotal, int* __restrict__ binBase,
    unsigned short* __restrict__ sbuf_src, unsigned char* __restrict__ sbuf_c,
    float* __restrict__ dinv, int* __restrict__ row_ptr,
    unsigned short* __restrict__ csr_src, int* bar,
    const float* __restrict__ x, const __half* __restrict__ W0h,
    const __half* __restrict__ W0l, __half* __restrict__ h2,
    int n, int E, int chunk) {
    __shared__ __align__(16) int smem[4864];   // 19456 B union
    int b = blockIdx.x;
    int t = threadIdx.x;

    // ---- gemm0 blocks: independent, no barriers ----
    if (b >= NBLK) {
        int g0 = b - NBLK;
        gemm0_lds_body(x, W0h, W0l, h2, n, g0 * 64, (__half*)smem);
        if (g0 + GEMM0_MEGA < GEMM0_TILES) {
            __syncthreads();
            gemm0_lds_body(x, W0h, W0l, h2, n, (g0 + GEMM0_MEGA) * 64, (__half*)smem);
        }
        return;
    }

    // ---- Phase 1: per-(block,bin) histogram ----
    {
        int* h = smem;
        for (int i = t; i < NBINS; i += 256) h[i] = 0;
        __syncthreads();
        int beg = b * chunk;
        int end = min(E, beg + chunk);
        if (beg < end) {
            int vend = beg + ((end - beg) & ~3);
            for (int i = beg + t * 4; i < vend; i += 1024) {
                int4 c4 = *(const int4*)(col + i);
                atomicAdd(&h[c4.x >> 8], 1);
                atomicAdd(&h[c4.y >> 8], 1);
                atomicAdd(&h[c4.z >> 8], 1);
                atomicAdd(&h[c4.w >> 8], 1);
            }
            int i = vend + t;
            if (i < end) atomicAdd(&h[col[i] >> 8], 1);
        }
        __syncthreads();
        for (int i = t; i < NBINS; i += 256)
            hist[i * NBLK + b] = h[i];  // bin-major, block-minor
    }
    prep_barrier(bar, NBLK);

    // ---- Phase 2: per-bin scan over blocks (b<NBINS) ----
    if (b < NBINS) {
        int* ss = smem;
        int v = hist[b * NBLK + t];
        ss[t] = v;
        __syncthreads();
#pragma unroll
        for (int off = 1; off < 256; off <<= 1) {
            int u = (t >= off) ? ss[t - off] : 0;
            __syncthreads();
            ss[t] += u;
            __syncthreads();
        }
        cursorBase[b * NBLK + t] = ss[t] - v;   // exclusive over blocks
        if (t == 255) binTotal[b] = ss[255];
    }
    prep_barrier(bar, 2 * NBLK);

    // ---- Phase 3: bin-sorted scatter ----
    {
        int* ss  = smem;
        int* cur = smem + 256;
        int v = (t < NBINS) ? binTotal[t] : 0;
        ss[t] = v;
        __syncthreads();
#pragma unroll
        for (int off = 1; off < 256; off <<= 1) {
            int u = (t >= off) ? ss[t - off] : 0;
            __syncthreads();
            ss[t] += u;
            __syncthreads();
        }
        int myBase = ss[t] - v;  // exclusive scan value for bin t
        if (t < NBINS) cur[t] = myBase + cursorBase[t * NBLK + b];
        if (b == 0) {
            if (t < NBINS) binBase[t] = myBase;
            if (t == 0) binBase[NBINS] = E;
        }
        __syncthreads();
        int beg = b * chunk;
        int end = min(E, beg + chunk);
        if (beg < end) {
            int vend = beg + ((end - beg) & ~3);
            for (int i = beg + t * 4; i < vend; i += 1024) {
                int4 c4 = *(const int4*)(col + i);
                int4 r4 = *(const int4*)(row + i);
                int p;
                p = atomicAdd(&cur[c4.x >> 8], 1); sbuf_src[p] = (unsigned short)r4.x; sbuf_c[p] = (unsigned char)(c4.x & 255);
                p = atomicAdd(&cur[c4.y >> 8], 1); sbuf_src[p] = (unsigned short)r4.y; sbuf_c[p] = (unsigned char)(c4.y & 255);
                p = atomicAdd(&cur[c4.z >> 8], 1); sbuf_src[p] = (unsigned short)r4.z; sbuf_c[p] = (unsigned char)(c4.z & 255);
                p = atomicAdd(&cur[c4.w >> 8], 1); sbuf_src[p] = (unsigned short)r4.w; sbuf_c[p] = (unsigned char)(c4.w & 255);
            }
            int i = vend + t;
            if (i < end) {
                int c = col[i];
                int p = atomicAdd(&cur[c >> 8], 1);
                sbuf_src[p] = (unsigned short)row[i];
                sbuf_c[p] = (unsigned char)(c & 255);
            }
        }
    }
    prep_barrier(bar, 3 * NBLK);

    // ---- Phase 4: CSR placement (b<NBINS) ----
    if (b < NBINS) {
        int* lcnt = smem;
        int* lcur = smem + 256;
        int* ss   = smem + 512;
        int* lbuf = smem + 768;   // LBUF_CAP ints
        lcnt[t] = 0;
        __syncthreads();
        int beg = binBase[b], end = binBase[b + 1];
        for (int j = beg + t; j < end; j += 256)
            atomicAdd(&lcnt[sbuf_c[j]], 1);
        __syncthreads();
        int deg = lcnt[t];
        int node = b * 256 + t;
        if (node < n) dinv[node] = rsqrtf((float)deg + 1.0f);
        ss[t] = deg;
        __syncthreads();
#pragma unroll
        for (int off = 1; off < 256; off <<= 1) {
            int u = (t >= off) ? ss[t - off] : 0;
            __syncthreads();
            ss[t] += u;
            __syncthreads();
        }
        int excl = ss[t] - deg;
        lcur[t] = excl;
        int total = ss[255];
        if (node < n) row_ptr[node] = beg + excl;
        if (b == 0 && t == 0) row_ptr[n] = E;
        __syncthreads();
        for (int j = beg + t; j < end; j += 256) {
            int c = sbuf_c[j];
            int pos = atomicAdd(&lcur[c], 1);
            lbuf[pos] = sbuf_src[j];
        }
        __syncthreads();
        for (int j = t; j < total; j += 256)
            csr_src[beg + j] = (unsigned short)lbuf[j];
    }
}

// ---------------- fused agg + GEMM: 16 nodes per block (FROZEN control) ----
// Pinned at ~51us / 67MB FETCH = per-XCD compulsory-miss floor.
template<int NC, bool HEAD>
__global__ __launch_bounds__(256) void agg_gemm_kernel(
    const __half* __restrict__ h2, const int* __restrict__ row_ptr,
    const unsigned short* __restrict__ csr_src, const float* __restrict__ dinv,
    const float* __restrict__ bias,
    const __half* __restrict__ Bh, const __half* __restrict__ Bl,
    const float* __restrict__ gbias, void* __restrict__ Cv, int n) {
    __shared__ __half Als[16][AROW];
    int wave = threadIdx.x >> 6;
    int lane = threadIdx.x & 63;
    int m0 = blockIdx.x << 4;

    // ---- Phase A: one node per 16-lane group ----
    int g = lane >> 4;          // group in wave
    int l16 = lane & 15;        // lane in group
    int baseLane = lane & 48;   // first lane of this group
    int lr = (wave << 2) + g;   // local row 0..15
    int wid = m0 + lr;
    const __half* hrow = h2 + (l16 << 3);  // this lane's 8-col slice of any row

    if (wid < n) {
        int beg = row_ptr[wid];
        int end = row_ptr[wid + 1];
        float dv = dinv[wid];
        float acc[8];
#pragma unroll
        for (int i = 0; i < 8; ++i) acc[i] = 0.f;

        for (int base = beg; base < end; base += 16) {
            int cnt = end - base;
            if (cnt > 16) cnt = 16;
            int msrc = 0;
            float mw = 0.f;
            if (l16 < cnt) {
                msrc = csr_src[base + l16];
                mw = dinv[msrc] * dv;
            }
            int j = 0;
            for (; j + 4 <= cnt; j += 4) {
                int s0 = __shfl(msrc, baseLane + j);
                int s1 = __shfl(msrc, baseLane + j + 1);
                int s2 = __shfl(msrc, baseLane + j + 2);
                int s3 = __shfl(msrc, baseLane + j + 3);
                float w0 = __shfl(mw, baseLane + j);
                float w1 = __shfl(mw, baseLane + j + 1);
                float w2 = __shfl(mw, baseLane + j + 2);
                float w3 = __shfl(mw, baseLane + j + 3);
                f16x8 v0 = *(const f16x8*)(hrow + ((size_t)s0 << 7));
                f16x8 v1 = *(const f16x8*)(hrow + ((size_t)s1 << 7));
                f16x8 v2 = *(const f16x8*)(hrow + ((size_t)s2 << 7));
                f16x8 v3 = *(const f16x8*)(hrow + ((size_t)s3 << 7));
#pragma unroll
                for (int i = 0; i < 8; ++i) {
                    acc[i] = fmaf((float)v0[i], w0, acc[i]);
                    acc[i] = fmaf((float)v1[i], w1, acc[i]);
                    acc[i] = fmaf((float)v2[i], w2, acc[i]);
                    acc[i] = fmaf((float)v3[i], w3, acc[i]);
                }
            }
            for (; j + 2 <= cnt; j += 2) {
                int s0 = __shfl(msrc, baseLane + j);
                int s1 = __shfl(msrc, baseLane + j + 1);
                float w0 = __shfl(mw, baseLane + j);
                float w1 = __shfl(mw, baseLane + j + 1);
                f16x8 v0 = *(const f16x8*)(hrow + ((size_t)s0 << 7));
                f16x8 v1 = *(const f16x8*)(hrow + ((size_t)s1 << 7));
#pragma unroll
                for (int i = 0; i < 8; ++i) {
                    acc[i] = fmaf((float)v0[i], w0, acc[i]);
                    acc[i] = fmaf((float)v1[i], w1, acc[i]);
                }
            }
            if (j < cnt) {
                int s0 = __shfl(msrc, baseLane + j);
                float w0 = __shfl(mw, baseLane + j);
                f16x8 v0 = *(const f16x8*)(hrow + ((size_t)s0 << 7));
#pragma unroll
                for (int i = 0; i < 8; ++i)
                    acc[i] = fmaf((float)v0[i], w0, acc[i]);
            }
        }
        // self loop + bias + relu -> fp16 row in LDS
        float sn = dv * dv;
        f16x8 sv = *(const f16x8*)(hrow + ((size_t)wid << 7));
        float4 ba = *(const float4*)(bias + (l16 << 3));
        float4 bb = *(const float4*)(bias + (l16 << 3) + 4);
        float o[8];
#pragma unroll
        for (int i = 0; i < 8; ++i) o[i] = fmaf((float)sv[i], sn, acc[i]);
        o[0] += ba.x; o[1] += ba.y; o[2] += ba.z; o[3] += ba.w;
        o[4] += bb.x; o[5] += bb.y; o[6] += bb.z; o[7] += bb.w;
        f16x8 pk;
#pragma unroll
        for (int i = 0; i < 8; ++i) pk[i] = (_Float16)fmaxf(o[i], 0.f);
        *(f16x8*)&Als[lr][l16 << 3] = pk;
    }
    __syncthreads();

    // ---- Phase B: 16-row GEMM tile, NT column tiles split across 4 waves ----
    constexpr int NT = NC / 16;         // 8 (hidden) or 4 (head)
    constexpr int TPW = NT / 4;         // tiles per wave: 2 or 1
    int mr = lane & 15;
    int kq = (lane >> 4) << 3;
    const __half* bh = Bh + (size_t)mr * 128 + kq;
    const __half* bl = Bl + (size_t)mr * 128 + kq;

    f32x4 acc[TPW];
#pragma unroll
    for (int t = 0; t < TPW; ++t) acc[t] = (f32x4){0.f, 0.f, 0.f, 0.f};
#pragma unroll
    for (int kc = 0; kc < 128; kc += 32) {
        f16x8 a = *(const f16x8*)&Als[mr][kq + kc];
#pragma unroll
        for (int t = 0; t < TPW; ++t) {
            int tile = wave * TPW + t;
            f16x8 wh = *(const f16x8*)(bh + (size_t)tile * 16 * 128 + kc);
            f16x8 wl = *(const f16x8*)(bl + (size_t)tile * 16 * 128 + kc);
            acc[t] = __builtin_amdgcn_mfma_f32_16x16x32_f16(a, wh, acc[t], 0, 0, 0);
            acc[t] = __builtin_amdgcn_mfma_f32_16x16x32_f16(a, wl, acc[t], 0, 0, 0);
        }
    }
    int r0 = m0 + ((lane >> 4) << 2);
    int cc = lane & 15;
#pragma unroll
    for (int t = 0; t < TPW; ++t) {
        int tile = wave * TPW + t;
        float bsv = HEAD ? gbias[tile * 16 + cc] : 0.f;
#pragma unroll
        for (int r = 0; r < 4; ++r) {
            if (r0 + r >= n) break;
            size_t idx = (size_t)(r0 + r) * NC + tile * 16 + cc;
            float val = acc[t][r] + bsv;
            if (HEAD)
                ((float*)Cv)[idx] = val;
            else
                ((__half*)Cv)[idx] = __float2half_rn(val);
        }
    }
}

extern "C" void kernel_launch(void* const* d_in, const int* in_sizes, int n_in,
                              void* d_out, int out_size, void* d_ws, size_t ws_size,
                              hipStream_t stream) {
    const float* x  = (const float*)d_in[0];
    const int* ei   = (const int*)d_in[1];
    const float* W0 = (const float*)d_in[2];
    const float* b0 = (const float*)d_in[3];
    const float* W1 = (const float*)d_in[4];
    const float* b1 = (const float*)d_in[5];
    const float* W2 = (const float*)d_in[6];
    const float* b2 = (const float*)d_in[7];
    const float* Wl = (const float*)d_in[8];
    const float* bl = (const float*)d_in[9];
    float* out = (float*)d_out;

    const int N = N_NODES;
    const int E = in_sizes[1] / 2;
    const int* row = ei;
    const int* col = ei + E;
    const int chunk = (((E + NBLK - 1) / NBLK) + 3) & ~3;  // 4-aligned chunks

    char* ws = (char*)d_ws;
    auto alloc = [&](size_t bytes) {
        char* p = ws;
        ws += (bytes + 255) & ~(size_t)255;
        return p;
    };
    int*   hist      = (int*)alloc((size_t)NBINS * NBLK * 4);
    int*   cursorBase= (int*)alloc((size_t)NBINS * NBLK * 4);
    int*   binTotal  = (int*)alloc((size_t)NBINS * 4);
    int*   binBase   = (int*)alloc((size_t)(NBINS + 1) * 4);
    int*   bar       = (int*)alloc(256);
    unsigned short* sbuf_src = (unsigned short*)alloc((size_t)E * 2);
    unsigned char*  sbuf_c   = (unsigned char*)alloc((size_t)E);
    int*   row_ptr = (int*)alloc((size_t)(N + 1) * 4);
    float* dinv    = (float*)alloc((size_t)N * 4);
    unsigned short* csr_src = (unsigned short*)alloc((size_t)E * 2);
    __half* h2a    = (__half*)alloc((size_t)N * HID * 2);
    __half* h2b    = (__half*)alloc((size_t)N * HID * 2);
    __half* Wt_h[4];
    __half* Wt_l[4];
    for (int i = 0; i < 3; ++i) {
        Wt_h[i] = (__half*)alloc((size_t)HID * HID * 2);
        Wt_l[i] = (__half*)alloc((size_t)HID * HID * 2);
    }
    Wt_h[3] = (__half*)alloc((size_t)CLS * HID * 2);
    Wt_l[3] = (__half*)alloc((size_t)CLS * HID * 2);

    // barrier counter must start at zero every run
    hipMemsetAsync(bar, 0, 256, stream);

    // K0: weight split (tiny; unblocks gemm0 inside the mega kernel)
    wsplit_kernel<<<WSPLIT_BLOCKS, 256, 0, stream>>>(W0, W1, W2, Wl,
        Wt_h[0], Wt_l[0], Wt_h[1], Wt_l[1], Wt_h[2], Wt_l[2], Wt_h[3], Wt_l[3]);

    // K1: mega prep chain (sw-barrier among 256 prep blocks) || gemm0 (768 blocks)
    prep_gemm0_mega_kernel<<<MEGA_BLOCKS, 256, 0, stream>>>(
        row, col, hist, cursorBase, binTotal, binBase, sbuf_src, sbuf_c,
        dinv, row_ptr, csr_src, bar, x, Wt_h[0], Wt_l[0], h2a, N, E, chunk);

    const int fusedBlocks = (N + 15) / 16;  // 3125

    // K2: agg(layer0) + GEMM@W1
    agg_gemm_kernel<128, false><<<fusedBlocks, 256, 0, stream>>>(
        h2a, row_ptr, csr_src, dinv, b0, Wt_h[1], Wt_l[1], nullptr, h2b, N);
    // K3: agg(layer1) + GEMM@W2
    agg_gemm_kernel<128, false><<<fusedBlocks, 256, 0, stream>>>(
        h2b, row_ptr, csr_src, dinv, b1, Wt_h[2], Wt_l[2], nullptr, h2a, N);
    // K4: agg(layer2) + head GEMM@Wl (+bl, fp32 out)
    agg_gemm_kernel<64, true><<<fusedBlocks, 256, 0, stream>>>(
        h2a, row_ptr, csr_src, dinv, b2, Wt_h[3], Wt_l[3], bl, out, N);
}

// Round 12
// 265.448 us; speedup vs baseline: 1.3104x; 1.3104x over previous
//
#include <hip/hip_runtime.h>
#include <hip/hip_fp16.h>

#define N_NODES 50000
#define HID 128
#define CLS 64

#define NBINS 196        // ceil(50000/256) node bins
#define NBLK 256         // hist/scatter blocks
#define LBUF_CAP 4096    // per-bin CSR staging (bin degree ~3277 + 14 sigma)
#define WTOT 57344       // 3*128*128 + 64*128 weight elements
#define GEMM0_BLOCKS 782 // ceil(3125 tiles / 4 waves)
#define AROW 136         // LDS row stride (128 + 8 pad -> 2-way bank aliasing, free)

typedef __attribute__((ext_vector_type(8))) _Float16 f16x8;
typedef __attribute__((ext_vector_type(4))) float f32x4;

// ---------------- K1: per-(block,bin) histogram + W split ----------------
__global__ __launch_bounds__(256) void hist_wsplit_kernel(
    const int* __restrict__ col, int* __restrict__ hist,
    const float* __restrict__ W0, const float* __restrict__ W1,
    const float* __restrict__ W2, const float* __restrict__ Wl,
    __half* __restrict__ o0h, __half* __restrict__ o0l,
    __half* __restrict__ o1h, __half* __restrict__ o1l,
    __half* __restrict__ o2h, __half* __restrict__ o2l,
    __half* __restrict__ o3h, __half* __restrict__ o3l,
    int E, int chunk) {
    int widx = blockIdx.x * 256 + threadIdx.x;
    if (widx < WTOT) {
        const float* W;
        __half *oh, *ol;
        int NCdim, local;
        if (widx < 16384)      { W = W0; oh = o0h; ol = o0l; NCdim = 128; local = widx; }
        else if (widx < 32768) { W = W1; oh = o1h; ol = o1l; NCdim = 128; local = widx - 16384; }
        else if (widx < 49152) { W = W2; oh = o2h; ol = o2l; NCdim = 128; local = widx - 32768; }
        else                   { W = Wl; oh = o3h; ol = o3l; NCdim = 64;  local = widx - 49152; }
        int nn = local >> 7;
        int k = local & 127;
        float v = W[(size_t)k * NCdim + nn];
        __half h = __float2half_rn(v);
        oh[local] = h;
        ol[local] = __float2half_rn(v - __half2float(h));
    }
    __shared__ int h[NBINS];
    for (int i = threadIdx.x; i < NBINS; i += 256) h[i] = 0;
    __syncthreads();
    int b = blockIdx.x;
    int beg = b * chunk;
    int end = min(E, beg + chunk);
    if (beg < end) {
        int vend = beg + ((end - beg) & ~3);
        for (int i = beg + threadIdx.x * 4; i < vend; i += 1024) {
            int4 c4 = *(const int4*)(col + i);
            atomicAdd(&h[c4.x >> 8], 1);
            atomicAdd(&h[c4.y >> 8], 1);
            atomicAdd(&h[c4.z >> 8], 1);
            atomicAdd(&h[c4.w >> 8], 1);
        }
        int i = vend + threadIdx.x;
        if (i < end) atomicAdd(&h[col[i] >> 8], 1);
    }
    __syncthreads();
    for (int i = threadIdx.x; i < NBINS; i += 256)
        hist[i * NBLK + b] = h[i];  // bin-major, block-minor
}

// ---------------- K1.5: per-bin scan over blocks ----------------
// One block per bin: exclusive-scan the bin's 256 per-block counts.
__global__ __launch_bounds__(256) void binscan_kernel(
    const int* __restrict__ hist, int* __restrict__ cursorBase,
    int* __restrict__ binTotal) {
    __shared__ int ss[256];
    int bin = blockIdx.x, t = threadIdx.x;
    int v = hist[bin * NBLK + t];
    ss[t] = v;
    __syncthreads();
#pragma unroll
    for (int off = 1; off < 256; off <<= 1) {
        int u = (t >= off) ? ss[t - off] : 0;
        __syncthreads();
        ss[t] += u;
        __syncthreads();
    }
    cursorBase[bin * NBLK + t] = ss[t] - v;   // exclusive over blocks
    if (t == 255) binTotal[bin] = ss[255];
}

// ---------------- K2: scatter (cursors from precomputed scan) ----------
__global__ __launch_bounds__(256) void scatter_kernel(
    const int* __restrict__ row, const int* __restrict__ col,
    const int* __restrict__ binTotal, const int* __restrict__ cursorBase,
    int* __restrict__ binBase_g,
    unsigned short* __restrict__ sbuf_src, unsigned char* __restrict__ sbuf_c,
    int E, int chunk) {
    __shared__ int ss[256];
    __shared__ int cur[NBINS];
    int b = blockIdx.x, t = threadIdx.x;
    int v = (t < NBINS) ? binTotal[t] : 0;
    ss[t] = v;
    __syncthreads();
#pragma unroll
    for (int off = 1; off < 256; off <<= 1) {
        int u = (t >= off) ? ss[t - off] : 0;
        __syncthreads();
        ss[t] += u;
        __syncthreads();
    }
    int myBase = ss[t] - v;  // exclusive scan value for bin t
    if (t < NBINS) cur[t] = myBase + cursorBase[t * NBLK + b];
    if (b == 0) {
        if (t < NBINS) binBase_g[t] = myBase;
        if (t == 0) binBase_g[NBINS] = E;
    }
    __syncthreads();
    int beg = b * chunk;
    int end = min(E, beg + chunk);
    if (beg >= end) return;
    int vend = beg + ((end - beg) & ~3);
    for (int i = beg + t * 4; i < vend; i += 1024) {
        int4 c4 = *(const int4*)(col + i);
        int4 r4 = *(const int4*)(row + i);
        int p;
        p = atomicAdd(&cur[c4.x >> 8], 1); sbuf_src[p] = (unsigned short)r4.x; sbuf_c[p] = (unsigned char)(c4.x & 255);
        p = atomicAdd(&cur[c4.y >> 8], 1); sbuf_src[p] = (unsigned short)r4.y; sbuf_c[p] = (unsigned char)(c4.y & 255);
        p = atomicAdd(&cur[c4.z >> 8], 1); sbuf_src[p] = (unsigned short)r4.z; sbuf_c[p] = (unsigned char)(c4.z & 255);
        p = atomicAdd(&cur[c4.w >> 8], 1); sbuf_src[p] = (unsigned short)r4.w; sbuf_c[p] = (unsigned char)(c4.w & 255);
    }
    int i = vend + t;
    if (i < end) {
        int c = col[i];
        int p = atomicAdd(&cur[c >> 8], 1);
        sbuf_src[p] = (unsigned short)row[i];
        sbuf_c[p] = (unsigned char)(c & 255);
    }
}

// ---------------- GEMM body for gemm-0 (A = x fp32, in-register convert) ----------
__device__ __forceinline__ void gemm0_body(
    const float* __restrict__ x, const __half* __restrict__ Bh,
    const __half* __restrict__ Bl, __half* __restrict__ C, int M, int rowTile) {
    constexpr int NT = 8;
    int lane = threadIdx.x & 63;
    int m0 = rowTile << 4;
    if (m0 >= M) return;
    int mr = lane & 15;
    int kq = (lane >> 4) << 3;

    const float*  af = x + (size_t)(m0 + mr) * 128 + kq;
    const __half* bh = Bh + (size_t)mr * 128 + kq;
    const __half* bl = Bl + (size_t)mr * 128 + kq;

    f32x4 acc[NT];
#pragma unroll
    for (int t = 0; t < NT; ++t) acc[t] = (f32x4){0.f, 0.f, 0.f, 0.f};
#pragma unroll
    for (int kc = 0; kc < 128; kc += 32) {
        float4 lo = *(const float4*)(af + kc);
        float4 hi = *(const float4*)(af + kc + 4);
        f16x8 a;
        a[0] = (_Float16)lo.x; a[1] = (_Float16)lo.y;
        a[2] = (_Float16)lo.z; a[3] = (_Float16)lo.w;
        a[4] = (_Float16)hi.x; a[5] = (_Float16)hi.y;
        a[6] = (_Float16)hi.z; a[7] = (_Float16)hi.w;
#pragma unroll
        for (int t = 0; t < NT; ++t) {
            f16x8 wh = *(const f16x8*)(bh + (size_t)t * 16 * 128 + kc);
            f16x8 wl = *(const f16x8*)(bl + (size_t)t * 16 * 128 + kc);
            acc[t] = __builtin_amdgcn_mfma_f32_16x16x32_f16(a, wh, acc[t], 0, 0, 0);
            acc[t] = __builtin_amdgcn_mfma_f32_16x16x32_f16(a, wl, acc[t], 0, 0, 0);
        }
    }
    int r0 = m0 + ((lane >> 4) << 2);
    int cc = lane & 15;
#pragma unroll
    for (int t = 0; t < NT; ++t)
#pragma unroll
        for (int r = 0; r < 4; ++r)
            C[(size_t)(r0 + r) * 128 + t * 16 + cc] =
                __float2half_rn(acc[t][r]);
}

// ---------------- K3: fused csr_place (blocks < NBINS) + GEMM-0 (rest) ------------
__global__ __launch_bounds__(256) void csrplace_gemm0_kernel(
    const int* __restrict__ binBase,
    const unsigned short* __restrict__ sbuf_src, const unsigned char* __restrict__ sbuf_c,
    float* __restrict__ dinv, int* __restrict__ row_ptr,
    unsigned short* __restrict__ csr_src,
    const float* __restrict__ x, const __half* __restrict__ W0h,
    const __half* __restrict__ W0l, __half* __restrict__ h2, int n, int E) {
    __shared__ int lcnt[256];
    __shared__ int lcur[256];
    __shared__ int ss[256];
    __shared__ int lbuf[LBUF_CAP];
    int b = blockIdx.x;
    if (b >= NBINS) {
        gemm0_body(x, W0h, W0l, h2, n, (b - NBINS) * 4 + (threadIdx.x >> 6));
        return;
    }
    int t = threadIdx.x;
    lcnt[t] = 0;
    __syncthreads();
    int beg = binBase[b], end = binBase[b + 1];
    for (int j = beg + t; j < end; j += 256)
        atomicAdd(&lcnt[sbuf_c[j]], 1);
    __syncthreads();
    int deg = lcnt[t];
    int node = b * 256 + t;
    if (node < n) dinv[node] = rsqrtf((float)deg + 1.0f);
    ss[t] = deg;
    __syncthreads();
#pragma unroll
    for (int off = 1; off < 256; off <<= 1) {
        int u = (t >= off) ? ss[t - off] : 0;
        __syncthreads();
        ss[t] += u;
        __syncthreads();
    }
    int excl = ss[t] - deg;
    lcur[t] = excl;
    int total = ss[255];
    if (node < n) row_ptr[node] = beg + excl;
    if (b == 0 && t == 0) row_ptr[n] = E;
    __syncthreads();
    for (int j = beg + t; j < end; j += 256) {
        int c = sbuf_c[j];
        int pos = atomicAdd(&lcur[c], 1);
        lbuf[pos] = sbuf_src[j];
    }
    __syncthreads();
    for (int j = t; j < total; j += 256)
        csr_src[beg + j] = (unsigned short)lbuf[j];
}

// ---------------- fused agg + GEMM: 16 nodes per block (FROZEN, best verified) -----
// Phase A: 4 waves x 4 groups; each 16-lane group owns one node, gathers full
// 256B h2 rows as 16 lanes x f16x8, unrolled 4-deep; relu'd fp16 rows to LDS.
// Phase B: 16-row MFMA tile against W (NC cols).
// Pinned at ~51us / 67MB FETCH = per-XCD compulsory-miss floor (R0/R1/R3/R6
// all plateau here; slicing and src-sorting both refuted).
template<int NC, bool HEAD>
__global__ __launch_bounds__(256) void agg_gemm_kernel(
    const __half* __restrict__ h2, const int* __restrict__ row_ptr,
    const unsigned short* __restrict__ csr_src, const float* __restrict__ dinv,
    const float* __restrict__ bias,
    const __half* __restrict__ Bh, const __half* __restrict__ Bl,
    const float* __restrict__ gbias, void* __restrict__ Cv, int n) {
    __shared__ __half Als[16][AROW];
    int wave = threadIdx.x >> 6;
    int lane = threadIdx.x & 63;
    int m0 = blockIdx.x << 4;

    // ---- Phase A: one node per 16-lane group ----
    int g = lane >> 4;          // group in wave
    int l16 = lane & 15;        // lane in group
    int baseLane = lane & 48;   // first lane of this group
    int lr = (wave << 2) + g;   // local row 0..15
    int wid = m0 + lr;
    const __half* hrow = h2 + (l16 << 3);  // this lane's 8-col slice of any row

    if (wid < n) {
        int beg = row_ptr[wid];
        int end = row_ptr[wid + 1];
        float dv = dinv[wid];
        float acc[8];
#pragma unroll
        for (int i = 0; i < 8; ++i) acc[i] = 0.f;

        for (int base = beg; base < end; base += 16) {
            int cnt = end - base;
            if (cnt > 16) cnt = 16;
            int msrc = 0;
            float mw = 0.f;
            if (l16 < cnt) {
                msrc = csr_src[base + l16];
                mw = dinv[msrc] * dv;
            }
            int j = 0;
            for (; j + 4 <= cnt; j += 4) {
                int s0 = __shfl(msrc, baseLane + j);
                int s1 = __shfl(msrc, baseLane + j + 1);
                int s2 = __shfl(msrc, baseLane + j + 2);
                int s3 = __shfl(msrc, baseLane + j + 3);
                float w0 = __shfl(mw, baseLane + j);
                float w1 = __shfl(mw, baseLane + j + 1);
                float w2 = __shfl(mw, baseLane + j + 2);
                float w3 = __shfl(mw, baseLane + j + 3);
                f16x8 v0 = *(const f16x8*)(hrow + ((size_t)s0 << 7));
                f16x8 v1 = *(const f16x8*)(hrow + ((size_t)s1 << 7));
                f16x8 v2 = *(const f16x8*)(hrow + ((size_t)s2 << 7));
                f16x8 v3 = *(const f16x8*)(hrow + ((size_t)s3 << 7));
#pragma unroll
                for (int i = 0; i < 8; ++i) {
                    acc[i] = fmaf((float)v0[i], w0, acc[i]);
                    acc[i] = fmaf((float)v1[i], w1, acc[i]);
                    acc[i] = fmaf((float)v2[i], w2, acc[i]);
                    acc[i] = fmaf((float)v3[i], w3, acc[i]);
                }
            }
            for (; j + 2 <= cnt; j += 2) {
                int s0 = __shfl(msrc, baseLane + j);
                int s1 = __shfl(msrc, baseLane + j + 1);
                float w0 = __shfl(mw, baseLane + j);
                float w1 = __shfl(mw, baseLane + j + 1);
                f16x8 v0 = *(const f16x8*)(hrow + ((size_t)s0 << 7));
                f16x8 v1 = *(const f16x8*)(hrow + ((size_t)s1 << 7));
#pragma unroll
                for (int i = 0; i < 8; ++i) {
                    acc[i] = fmaf((float)v0[i], w0, acc[i]);
                    acc[i] = fmaf((float)v1[i], w1, acc[i]);
                }
            }
            if (j < cnt) {
                int s0 = __shfl(msrc, baseLane + j);
                float w0 = __shfl(mw, baseLane + j);
                f16x8 v0 = *(const f16x8*)(hrow + ((size_t)s0 << 7));
#pragma unroll
                for (int i = 0; i < 8; ++i)
                    acc[i] = fmaf((float)v0[i], w0, acc[i]);
            }
        }
        // self loop + bias + relu -> fp16 row in LDS
        float sn = dv * dv;
        f16x8 sv = *(const f16x8*)(hrow + ((size_t)wid << 7));
        float4 ba = *(const float4*)(bias + (l16 << 3));
        float4 bb = *(const float4*)(bias + (l16 << 3) + 4);
        float o[8];
#pragma unroll
        for (int i = 0; i < 8; ++i) o[i] = fmaf((float)sv[i], sn, acc[i]);
        o[0] += ba.x; o[1] += ba.y; o[2] += ba.z; o[3] += ba.w;
        o[4] += bb.x; o[5] += bb.y; o[6] += bb.z; o[7] += bb.w;
        f16x8 pk;
#pragma unroll
        for (int i = 0; i < 8; ++i) pk[i] = (_Float16)fmaxf(o[i], 0.f);
        *(f16x8*)&Als[lr][l16 << 3] = pk;
    }
    __syncthreads();

    // ---- Phase B: 16-row GEMM tile, NT column tiles split across 4 waves ----
    constexpr int NT = NC / 16;         // 8 (hidden) or 4 (head)
    constexpr int TPW = NT / 4;         // tiles per wave: 2 or 1
    int mr = lane & 15;
    int kq = (lane >> 4) << 3;
    const __half* bh = Bh + (size_t)mr * 128 + kq;
    const __half* bl = Bl + (size_t)mr * 128 + kq;

    f32x4 acc[TPW];
#pragma unroll
    for (int t = 0; t < TPW; ++t) acc[t] = (f32x4){0.f, 0.f, 0.f, 0.f};
#pragma unroll
    for (int kc = 0; kc < 128; kc += 32) {
        f16x8 a = *(const f16x8*)&Als[mr][kq + kc];
#pragma unroll
        for (int t = 0; t < TPW; ++t) {
            int tile = wave * TPW + t;
            f16x8 wh = *(const f16x8*)(bh + (size_t)tile * 16 * 128 + kc);
            f16x8 wl = *(const f16x8*)(bl + (size_t)tile * 16 * 128 + kc);
            acc[t] = __builtin_amdgcn_mfma_f32_16x16x32_f16(a, wh, acc[t], 0, 0, 0);
            acc[t] = __builtin_amdgcn_mfma_f32_16x16x32_f16(a, wl, acc[t], 0, 0, 0);
        }
    }
    int r0 = m0 + ((lane >> 4) << 2);
    int cc = lane & 15;
#pragma unroll
    for (int t = 0; t < TPW; ++t) {
        int tile = wave * TPW + t;
        float bsv = HEAD ? gbias[tile * 16 + cc] : 0.f;
#pragma unroll
        for (int r = 0; r < 4; ++r) {
            if (r0 + r >= n) break;
            size_t idx = (size_t)(r0 + r) * NC + tile * 16 + cc;
            float val = acc[t][r] + bsv;
            if (HEAD)
                ((float*)Cv)[idx] = val;
            else
                ((__half*)Cv)[idx] = __float2half_rn(val);
        }
    }
}

extern "C" void kernel_launch(void* const* d_in, const int* in_sizes, int n_in,
                              void* d_out, int out_size, void* d_ws, size_t ws_size,
                              hipStream_t stream) {
    const float* x  = (const float*)d_in[0];
    const int* ei   = (const int*)d_in[1];
    const float* W0 = (const float*)d_in[2];
    const float* b0 = (const float*)d_in[3];
    const float* W1 = (const float*)d_in[4];
    const float* b1 = (const float*)d_in[5];
    const float* W2 = (const float*)d_in[6];
    const float* b2 = (const float*)d_in[7];
    const float* Wl = (const float*)d_in[8];
    const float* bl = (const float*)d_in[9];
    float* out = (float*)d_out;

    const int N = N_NODES;
    const int E = in_sizes[1] / 2;
    const int* row = ei;
    const int* col = ei + E;
    const int chunk = (((E + NBLK - 1) / NBLK) + 3) & ~3;  // 4-aligned chunks

    char* ws = (char*)d_ws;
    auto alloc = [&](size_t bytes) {
        char* p = ws;
        ws += (bytes + 255) & ~(size_t)255;
        return p;
    };
    int*   hist      = (int*)alloc((size_t)NBINS * NBLK * 4);
    int*   cursorBase= (int*)alloc((size_t)NBINS * NBLK * 4);
    int*   binTotal  = (int*)alloc((size_t)NBINS * 4);
    int*   binBase   = (int*)alloc((size_t)(NBINS + 1) * 4);
    unsigned short* sbuf_src = (unsigned short*)alloc((size_t)E * 2);
    unsigned char*  sbuf_c   = (unsigned char*)alloc((size_t)E);
    int*   row_ptr = (int*)alloc((size_t)(N + 1) * 4);
    float* dinv    = (float*)alloc((size_t)N * 4);
    unsigned short* csr_src = (unsigned short*)alloc((size_t)E * 2);
    __half* h2a    = (__half*)alloc((size_t)N * HID * 2);
    __half* h2b    = (__half*)alloc((size_t)N * HID * 2);
    __half* Wt_h[4];
    __half* Wt_l[4];
    for (int i = 0; i < 3; ++i) {
        Wt_h[i] = (__half*)alloc((size_t)HID * HID * 2);
        Wt_l[i] = (__half*)alloc((size_t)HID * HID * 2);
    }
    Wt_h[3] = (__half*)alloc((size_t)CLS * HID * 2);
    Wt_l[3] = (__half*)alloc((size_t)CLS * HID * 2);

    // K1: histogram + weight split
    hist_wsplit_kernel<<<NBLK, 256, 0, stream>>>(col, hist, W0, W1, W2, Wl,
        Wt_h[0], Wt_l[0], Wt_h[1], Wt_l[1], Wt_h[2], Wt_l[2], Wt_h[3], Wt_l[3], E, chunk);
    // K1.5: per-bin scan over blocks (replaces per-block hist rescan)
    binscan_kernel<<<NBINS, 256, 0, stream>>>(hist, cursorBase, binTotal);
    // K2: bin-sorted scatter
    scatter_kernel<<<NBLK, 256, 0, stream>>>(row, col, binTotal, cursorBase,
        binBase, sbuf_src, sbuf_c, E, chunk);
    // K3: CSR placement fused with GEMM-0 (independent workloads)
    csrplace_gemm0_kernel<<<NBINS + GEMM0_BLOCKS, 256, 0, stream>>>(
        binBase, sbuf_src, sbuf_c, dinv, row_ptr, csr_src,
        x, Wt_h[0], Wt_l[0], h2a, N, E);

    const int fusedBlocks = (N + 15) / 16;  // 3125

    // K4: agg(layer0) + GEMM@W1
    agg_gemm_kernel<128, false><<<fusedBlocks, 256, 0, stream>>>(
        h2a, row_ptr, csr_src, dinv, b0, Wt_h[1], Wt_l[1], nullptr, h2b, N);
    // K5: agg(layer1) + GEMM@W2
    agg_gemm_kernel<128, false><<<fusedBlocks, 256, 0, stream>>>(
        h2b, row_ptr, csr_src, dinv, b1, Wt_h[2], Wt_l[2], nullptr, h2a, N);
    // K6: agg(layer2) + head GEMM@Wl (+bl, fp32 out)
    agg_gemm_kernel<64, true><<<fusedBlocks, 256, 0, stream>>>(
        h2a, row_ptr, csr_src, dinv, b2, Wt_h[3], Wt_l[3], bl, out, N);
}